// Round 6
// baseline (245.148 us; speedup 1.0000x reference)
//
#include <hip/hip_runtime.h>
#include <math.h>

// Problem constants (B,N,C fixed by the reference setup).
#define BB 16
#define NN 2048
#define CC 64
#define TPB 256
#define RPB 16            // rows per block; all 4 waves share them
#define E_CONST 2.71828182845904523536f

__device__ inline float rfl(float v) {
    return __int_as_float(__builtin_amdgcn_readfirstlane(__float_as_int(v)));
}

// ---------------------------------------------------------------------------
// K_pre: zero the A accumulator (d_out) everywhere; blocks 0..BB-1 also run
// ballot-based kept/pruned compaction for batch b and zero S[b,:].
// ---------------------------------------------------------------------------
__global__ __launch_bounds__(TPB) void k_pre(const float* __restrict__ keep,
                                             float* __restrict__ outz,
                                             float* __restrict__ S,
                                             int* __restrict__ cntP,
                                             int* __restrict__ cntK,
                                             int* __restrict__ listP,
                                             int* __restrict__ listK) {
    const int tid = threadIdx.x, lane = tid & 63;

    // zero 1024 float4 of out per block (512 blocks x 16 KB = 8 MB)
    float4* o4 = (float4*)outz + (size_t)blockIdx.x * 1024;
    float4 z = {0.0f, 0.0f, 0.0f, 0.0f};
#pragma unroll
    for (int i = 0; i < 4; ++i) o4[i * TPB + tid] = z;

    const int b = blockIdx.x;
    if (b >= BB) return;

    __shared__ int cP, cK;
    if (tid == 0) { cP = 0; cK = 0; }
    __syncthreads();
    for (int i = tid; i < NN; i += TPB) S[b * NN + i] = 0.0f;
    const unsigned long long lt = (lane == 63) ? 0x7fffffffffffffffull
                                               : ((1ull << lane) - 1ull);
#pragma unroll
    for (int it = 0; it < NN / TPB; ++it) {
        int n = it * TPB + tid;
        bool kp = keep[b * NN + n] != 0.0f;
        unsigned long long mk = __ballot(kp);
        int nk = __popcll(mk);
        int bk = 0, bp = 0;
        if (lane == 0) {
            bk = atomicAdd(&cK, nk);
            bp = atomicAdd(&cP, 64 - nk);
        }
        bk = __shfl(bk, 0); bp = __shfl(bp, 0);
        int pk = __popcll(mk & lt);
        if (kp) listK[b * NN + bk + pk] = n;
        else    listP[b * NN + bp + (lane - pk)] = n;
    }
    __syncthreads();
    if (tid == 0) { cntP[b] = cP; cntK[b] = cK; }
}

// ---------------------------------------------------------------------------
// K_pre2: build colM[b][k4][colp] float4 = k-quad of kept column colp, scaled
// by its inverse L2 norm (computed inline from the same 16 loads); zeros for
// colp >= K.  Writes coalesced.
// ---------------------------------------------------------------------------
__global__ __launch_bounds__(TPB) void k_pre2(const float* __restrict__ x,
                                              const int* __restrict__ cntK,
                                              const int* __restrict__ listK,
                                              float4* __restrict__ colM) {
    const int b = blockIdx.y;
    const int colp = blockIdx.x * TPB + threadIdx.x;
    const int K = cntK[b];
    bool ok = colp < K;
    int tok = ok ? listK[b * NN + colp] : 0;
    const float4* x4 = (const float4*)(x + (size_t)b * NN * CC);
    float4 v[16];
    float sq = 0.0f;
#pragma unroll
    for (int k4 = 0; k4 < 16; ++k4) {
        v[k4] = x4[(size_t)tok * 16 + k4];
        sq += v[k4].x * v[k4].x + v[k4].y * v[k4].y
            + v[k4].z * v[k4].z + v[k4].w * v[k4].w;
    }
    float iv = ok ? 1.0f / (sqrtf(sq) + 1e-6f) : 0.0f;
#pragma unroll
    for (int k4 = 0; k4 < 16; ++k4) {
        float4 w = v[k4];
        w.x *= iv; w.y *= iv; w.z *= iv; w.w *= iv;
        colM[((size_t)b * 16 + k4) * NN + colp] = w;
    }
}

// ---------------------------------------------------------------------------
// K3: GEMM-argmax.  Block = 16 pruned rows shared by 4 waves; waves split the
// kept columns 4-way (no redundant col reads inside a block).
//  - rows: wave-uniform scalar values (readfirstlane -> SGPR; SMEM pipe),
//    FMA reads 1 sgpr + 1 vgpr -> zero L1/LDS cost for rows.
//  - cols: 4 coalesced float4 streams per lane from colM (vmcnt only).
//  - per k4: 256 FMA instr (512 cyc) vs 4 KB col data = 32 B/cyc/CU demand
//    at full VALU -- half the L1 ceiling (the R4/R5 binding resource).
//  - ties: running max + 8-bit (t,j) mask; cross-wave merge via tiny LDS.
// ---------------------------------------------------------------------------
__global__ __launch_bounds__(TPB, 3) void k_argmax(
    const float* __restrict__ x,      // [B,N,C]
    const float4* __restrict__ colM,  // [B,16,N] float4
    const int*   __restrict__ cntP,
    const int*   __restrict__ cntK,
    const int*   __restrict__ listP,
    const int*   __restrict__ listK,
    float* __restrict__ S,            // [B,N]   zeroed by k_pre
    float* __restrict__ A) {          // [B,N,C] zeroed by k_pre; aliases d_out

    const int b = blockIdx.y;
    const int P = cntP[b], K = cntK[b];
    const int base = blockIdx.x * RPB;
    if (base >= P) return;

    const int tid = threadIdx.x;
    const int w = tid >> 6;           // wave = column quarter
    const int lane = tid & 63;

    __shared__ float wm[4][RPB];

    int rtok[RPB];
    const float* rowp[RPB];
#pragma unroll
    for (int r = 0; r < RPB; ++r) {
        int rid = base + r;
        int tok = (rid < P) ? listP[b * NN + rid] : 0;
        tok = __builtin_amdgcn_readfirstlane(tok);
        rtok[r] = tok;
        rowp[r] = x + (size_t)(b * NN + tok) * CC;
    }
    const float4* cm = colM + (size_t)b * 16 * NN;

    float    tmax[RPB];
    unsigned msk[RPB];
#pragma unroll
    for (int r = 0; r < RPB; ++r) { tmax[r] = -3.0e38f; msk[r] = 0u; }

    for (int t = 0; t < 2; ++t) {
        const int cstart = t * 1024 + w * 256;   // this wave's 256-col segment
        if (cstart >= K) break;                  // wave-uniform

        float acc[RPB][4];
#pragma unroll
        for (int r = 0; r < RPB; ++r)
#pragma unroll
            for (int j = 0; j < 4; ++j) acc[r][j] = 0.0f;

#pragma unroll 4
        for (int k4 = 0; k4 < 16; ++k4) {
            // rows: wave-uniform k-quads, forced into SGPRs
            float4 rq[RPB];
#pragma unroll
            for (int r = 0; r < RPB; ++r) {
                float4 t4 = *(const float4*)(rowp[r] + k4 * 4);
                rq[r].x = rfl(t4.x); rq[r].y = rfl(t4.y);
                rq[r].z = rfl(t4.z); rq[r].w = rfl(t4.w);
            }
            // cols: 4 coalesced float4 streams
            const float4* cmk = cm + (size_t)k4 * NN + cstart + lane;
            float4 cv0 = cmk[0], cv1 = cmk[64], cv2 = cmk[128], cv3 = cmk[192];
#pragma unroll
            for (int r = 0; r < RPB; ++r) {
                acc[r][0] = fmaf(rq[r].x, cv0.x, fmaf(rq[r].y, cv0.y,
                            fmaf(rq[r].z, cv0.z, fmaf(rq[r].w, cv0.w, acc[r][0]))));
                acc[r][1] = fmaf(rq[r].x, cv1.x, fmaf(rq[r].y, cv1.y,
                            fmaf(rq[r].z, cv1.z, fmaf(rq[r].w, cv1.w, acc[r][1]))));
                acc[r][2] = fmaf(rq[r].x, cv2.x, fmaf(rq[r].y, cv2.y,
                            fmaf(rq[r].z, cv2.z, fmaf(rq[r].w, cv2.w, acc[r][2]))));
                acc[r][3] = fmaf(rq[r].x, cv3.x, fmaf(rq[r].y, cv3.y,
                            fmaf(rq[r].z, cv3.z, fmaf(rq[r].w, cv3.w, acc[r][3]))));
            }
        }

        // running max + tie mask (bit = t*4 + j, 8 bits total)
#pragma unroll
        for (int r = 0; r < RPB; ++r)
#pragma unroll
            for (int j = 0; j < 4; ++j) {
                int colp = cstart + j * 64 + lane;
                float s = (colp < K) ? acc[r][j] : -1.0e30f;
                unsigned bit = 1u << ((t << 2) | j);
                if (s > tmax[r])       { tmax[r] = s; msk[r] = bit; }
                else if (s == tmax[r])  msk[r] |= bit;
            }
    }

    // ---- cross-wave max exchange ----
#pragma unroll
    for (int r = 0; r < RPB; ++r) {
        float m = tmax[r];
#pragma unroll
        for (int off = 32; off; off >>= 1) m = fmaxf(m, __shfl_xor(m, off, 64));
        if (lane == 0) wm[w][r] = m;
    }
    __syncthreads();

    // ---- edge emission: every wave emits its own matching columns ----
    const int nvr = min(RPB, P - base);
    for (int r = 0; r < nvr; ++r) {
        float m = fmaxf(fmaxf(wm[0][r], wm[1][r]), fmaxf(wm[2][r], wm[3][r]));
        int src = rtok[r];
        float xv = x[(size_t)(b * NN + src) * CC + lane];
        float sq = xv * xv;
#pragma unroll
        for (int off = 32; off; off >>= 1) sq += __shfl_xor(sq, off, 64);
        float ivr = 1.0f / (sqrtf(sq) + 1e-6f);
        float wgt = expf(m * ivr);
        unsigned long long bal = __ballot(tmax[r] == m && msk[r] != 0u);
        while (bal) {
            int sl = __ffsll(bal) - 1;
            bal &= bal - 1;
            unsigned mm = __shfl(msk[r], sl);
            while (mm) {
                int bit = __ffs(mm) - 1;
                mm &= mm - 1;
                int colp = ((bit >> 2) * 1024) + w * 256 + ((bit & 3) * 64) + sl;
                int dst = listK[b * NN + colp];
                atomicAdd(&A[(size_t)(b * NN + dst) * CC + lane], wgt * xv);
                if (lane == 0) atomicAdd(&S[b * NN + dst], wgt);
            }
        }
    }
}

// ---------------------------------------------------------------------------
// K4: out = (e*x + A) / (e + S).  A aliases d_out (in-place), float4.
// ---------------------------------------------------------------------------
__global__ __launch_bounds__(TPB) void k_finalize(const float* __restrict__ x,
                                                  const float* __restrict__ S,
                                                  float* __restrict__ out) {
    int i = blockIdx.x * TPB + threadIdx.x;
    int row = i >> 4;
    float inv = 1.0f / (E_CONST + S[row]);
    float4 xv = ((const float4*)x)[i];
    float4 av = ((float4*)out)[i];
    float4 o;
    o.x = (xv.x * E_CONST + av.x) * inv;
    o.y = (xv.y * E_CONST + av.y) * inv;
    o.z = (xv.z * E_CONST + av.z) * inv;
    o.w = (xv.w * E_CONST + av.w) * inv;
    ((float4*)out)[i] = o;
}

// ---------------------------------------------------------------------------
extern "C" void kernel_launch(void* const* d_in, const int* in_sizes, int n_in,
                              void* d_out, int out_size, void* d_ws, size_t ws_size,
                              hipStream_t stream) {
    const float* x    = (const float*)d_in[0];
    const float* keep = (const float*)d_in[2];
    float* out = (float*)d_out;

    // ws: (reserved 128KB) | S 128KB | cnts 128B | listP 128KB | listK 128KB | colM 8MB
    char* ws = (char*)d_ws;
    float* S    = (float*)(ws + (128 << 10));
    int*   cntP = (int*)(ws + (256 << 10));
    int*   cntK = cntP + 16;
    int*   listP = (int*)(ws + (256 << 10) + 128);
    int*   listK = listP + BB * NN;
    float4* colM = (float4*)(ws + (1 << 20));

    k_pre<<<512, TPB, 0, stream>>>(keep, out, S, cntP, cntK, listP, listK);

    dim3 gp2(NN / TPB, BB);
    k_pre2<<<gp2, TPB, 0, stream>>>(x, cntK, listK, colM);

    dim3 ga(NN / RPB, BB);
    k_argmax<<<ga, TPB, 0, stream>>>(x, colM, cntP, cntK, listP, listK, S, out);

    k_finalize<<<(BB * NN * CC / 4) / TPB, TPB, 0, stream>>>(x, S, out);
}

// Round 7
// 216.019 us; speedup vs baseline: 1.1348x; 1.1348x over previous
//
#include <hip/hip_runtime.h>
#include <math.h>

// Problem constants (B,N,C fixed by the reference setup).
#define BB 16
#define NN 2048
#define CC 64
#define TPB 256
#define MROWS 32          // pruned rows per block (4 row-groups x 8 rows)
#define E_CONST 2.71828182845904523536f

// ---------------------------------------------------------------------------
// K_pre: zero the A accumulator (d_out) everywhere; blocks 0..BB-1 also run
// ballot-based kept/pruned compaction for batch b and zero S[b,:].
// ---------------------------------------------------------------------------
__global__ __launch_bounds__(TPB) void k_pre(const float* __restrict__ keep,
                                             float* __restrict__ outz,
                                             float* __restrict__ S,
                                             int* __restrict__ cntP,
                                             int* __restrict__ cntK,
                                             int* __restrict__ listP,
                                             int* __restrict__ listK) {
    const int tid = threadIdx.x, lane = tid & 63;

    // zero 1024 float4 of out per block (512 blocks x 16 KB = 8.39 MB)
    float4* o4 = (float4*)outz + (size_t)blockIdx.x * 1024;
    float4 z = {0.0f, 0.0f, 0.0f, 0.0f};
#pragma unroll
    for (int i = 0; i < 4; ++i) o4[i * TPB + tid] = z;

    const int b = blockIdx.x;
    if (b >= BB) return;

    __shared__ int cP, cK;
    if (tid == 0) { cP = 0; cK = 0; }
    __syncthreads();
    for (int i = tid; i < NN; i += TPB) S[b * NN + i] = 0.0f;
    const unsigned long long lt = (lane == 63) ? 0x7fffffffffffffffull
                                               : ((1ull << lane) - 1ull);
#pragma unroll
    for (int it = 0; it < NN / TPB; ++it) {
        int n = it * TPB + tid;
        bool kp = keep[b * NN + n] != 0.0f;
        unsigned long long mk = __ballot(kp);
        int nk = __popcll(mk);
        int bk = 0, bp = 0;
        if (lane == 0) {
            bk = atomicAdd(&cK, nk);
            bp = atomicAdd(&cP, 64 - nk);
        }
        bk = __shfl(bk, 0); bp = __shfl(bp, 0);
        int pk = __popcll(mk & lt);
        if (kp) listK[b * NN + bk + pk] = n;
        else    listP[b * NN + bp + (lane - pk)] = n;
    }
    __syncthreads();
    if (tid == 0) { cntP[b] = cP; cntK[b] = cK; }
}

// ---------------------------------------------------------------------------
// K_pre2: build colM[b][k4][colp] float4 = k-quad of kept column colp, scaled
// by its inverse L2 norm (computed inline); zeros for colp >= K.
// ---------------------------------------------------------------------------
__global__ __launch_bounds__(TPB) void k_pre2(const float* __restrict__ x,
                                              const int* __restrict__ cntK,
                                              const int* __restrict__ listK,
                                              float4* __restrict__ colM) {
    const int b = blockIdx.y;
    const int colp = blockIdx.x * TPB + threadIdx.x;
    const int K = cntK[b];
    bool ok = colp < K;
    int tok = ok ? listK[b * NN + colp] : 0;
    const float4* x4 = (const float4*)(x + (size_t)b * NN * CC);
    float4 v[16];
    float sq = 0.0f;
#pragma unroll
    for (int k4 = 0; k4 < 16; ++k4) {
        v[k4] = x4[(size_t)tok * 16 + k4];
        sq += v[k4].x * v[k4].x + v[k4].y * v[k4].y
            + v[k4].z * v[k4].z + v[k4].w * v[k4].w;
    }
    float iv = ok ? 1.0f / (sqrtf(sq) + 1e-6f) : 0.0f;
#pragma unroll
    for (int k4 = 0; k4 < 16; ++k4) {
        float4 w = v[k4];
        w.x *= iv; w.y *= iv; w.z *= iv; w.w *= iv;
        colM[((size_t)b * 16 + k4) * NN + colp] = w;
    }
}

// ---------------------------------------------------------------------------
// K3: GEMM-argmax.  Block = 512 threads / 8 waves = 4 row-groups (8 rows
// each) x 2 col-halves.  Inner loop identical to the proven R5 shape
// (VGPR 68, no spills): 8 rows broadcast from global, 8 coalesced float4
// col streams from colM, 64 dot4-accumulators.
//  - waves interleave 512-col tiles over the DYNAMIC tile count (no idle
//    half when K~1024); argmax merged across halves via LDS + one barrier.
//  - 1-D grid, b = id&15: batch -> XCD pinning (mod 8) keeps each XCD's
//    colM working set at ~1 MB -> L2-resident.
// ---------------------------------------------------------------------------
__global__ __launch_bounds__(512, 2) void k_argmax(
    const float* __restrict__ x,      // [B,N,C]
    const float4* __restrict__ colM,  // [B,16,N] float4
    const int*   __restrict__ cntP,
    const int*   __restrict__ cntK,
    const int*   __restrict__ listP,
    const int*   __restrict__ listK,
    float* __restrict__ S,            // [B,N]   zeroed by k_pre
    float* __restrict__ A) {          // [B,N,C] zeroed by k_pre; aliases d_out

    const int b    = blockIdx.x & 15;
    const int tilei = blockIdx.x >> 4;
    const int P = cntP[b], K = cntK[b];
    const int base = tilei * MROWS;
    if (base >= P) return;            // block-uniform exit

    const int tid  = threadIdx.x;
    const int w    = tid >> 6;        // wave 0..7
    const int g    = w & 3;           // row group
    const int h    = w >> 2;          // col half
    const int lane = tid & 63;

    __shared__ float wm[8][8];

    int rtok[8];
#pragma unroll
    for (int r = 0; r < 8; ++r) {
        int rid = base + g * 8 + r;
        int tok = (rid < P) ? listP[b * NN + rid] : 0;
        rtok[r] = __builtin_amdgcn_readfirstlane(tok);
    }
    const float4* x4 = (const float4*)(x + (size_t)b * NN * CC);
    const float4* cm = colM + (size_t)b * 16 * NN;

    float    tmax[8];
    unsigned msk[8];
#pragma unroll
    for (int r = 0; r < 8; ++r) { tmax[r] = -3.0e38f; msk[r] = 0u; }

    const int ntiles = (K + 511) >> 9;              // dynamic, <= 4

    for (int tl = 0; tl < 2; ++tl) {
        const int tile = h + 2 * tl;                // halves interleave tiles
        if (tile >= ntiles) break;                  // wave-uniform
        const int cstart = tile * 512;

        float acc[8][8];
#pragma unroll
        for (int r = 0; r < 8; ++r)
#pragma unroll
            for (int j = 0; j < 8; ++j) acc[r][j] = 0.0f;

#pragma unroll 2
        for (int k4 = 0; k4 < 16; ++k4) {
            float4 rv[8];
#pragma unroll
            for (int r = 0; r < 8; ++r)             // wave-uniform 16B loads
                rv[r] = x4[(size_t)rtok[r] * 16 + k4];
            const float4* cmk = cm + (size_t)k4 * NN + cstart + lane;
            float4 cv[8];
#pragma unroll
            for (int j = 0; j < 8; ++j)             // coalesced b128 streams
                cv[j] = cmk[j * 64];
#pragma unroll
            for (int r = 0; r < 8; ++r)
#pragma unroll
                for (int j = 0; j < 8; ++j)
                    acc[r][j] = fmaf(rv[r].x, cv[j].x,
                                fmaf(rv[r].y, cv[j].y,
                                fmaf(rv[r].z, cv[j].z,
                                fmaf(rv[r].w, cv[j].w, acc[r][j]))));
        }

#pragma unroll
        for (int r = 0; r < 8; ++r)
#pragma unroll
            for (int j = 0; j < 8; ++j) {
                int colp = cstart + j * 64 + lane;
                float s = (colp < K) ? acc[r][j] : -1.0e30f;
                unsigned bit = 1u << ((tl << 3) | j);
                if (s > tmax[r])       { tmax[r] = s; msk[r] = bit; }
                else if (s == tmax[r])  msk[r] |= bit;
            }
    }

    // ---- wave maxima -> LDS ----
#pragma unroll
    for (int r = 0; r < 8; ++r) {
        float m = tmax[r];
#pragma unroll
        for (int off = 32; off; off >>= 1) m = fmaxf(m, __shfl_xor(m, off, 64));
        if (lane == 0) wm[w][r] = m;
    }
    __syncthreads();

    // ---- edge emission: each wave emits its own matching columns ----
    const int nvr = min(8, P - base - g * 8);       // may be <= 0
    for (int r = 0; r < 8; ++r) {
        if (r >= nvr) break;
        float m = fmaxf(wm[g][r], wm[g + 4][r]);    // merge col halves
        int src = rtok[r];
        float xv = x[(size_t)(b * NN + src) * CC + lane];
        float sq = xv * xv;
#pragma unroll
        for (int off = 32; off; off >>= 1) sq += __shfl_xor(sq, off, 64);
        float ivr = 1.0f / (sqrtf(sq) + 1e-6f);
        float wgt = expf(m * ivr);
        unsigned long long bal = __ballot(tmax[r] == m && msk[r] != 0u);
        while (bal) {
            int sl = __ffsll(bal) - 1;
            bal &= bal - 1;
            unsigned mm = __shfl(msk[r], sl);
            while (mm) {
                int bit = __ffs(mm) - 1;
                mm &= mm - 1;
                int colp = (h + 2 * (bit >> 3)) * 512 + (bit & 7) * 64 + sl;
                int dst = listK[b * NN + colp];
                atomicAdd(&A[(size_t)(b * NN + dst) * CC + lane], wgt * xv);
                if (lane == 0) atomicAdd(&S[b * NN + dst], wgt);
            }
        }
    }
}

// ---------------------------------------------------------------------------
// K4: out = (e*x + A) / (e + S).  A aliases d_out (in-place), float4.
// ---------------------------------------------------------------------------
__global__ __launch_bounds__(TPB) void k_finalize(const float* __restrict__ x,
                                                  const float* __restrict__ S,
                                                  float* __restrict__ out) {
    int i = blockIdx.x * TPB + threadIdx.x;
    int row = i >> 4;
    float inv = 1.0f / (E_CONST + S[row]);
    float4 xv = ((const float4*)x)[i];
    float4 av = ((float4*)out)[i];
    float4 o;
    o.x = (xv.x * E_CONST + av.x) * inv;
    o.y = (xv.y * E_CONST + av.y) * inv;
    o.z = (xv.z * E_CONST + av.z) * inv;
    o.w = (xv.w * E_CONST + av.w) * inv;
    ((float4*)out)[i] = o;
}

// ---------------------------------------------------------------------------
extern "C" void kernel_launch(void* const* d_in, const int* in_sizes, int n_in,
                              void* d_out, int out_size, void* d_ws, size_t ws_size,
                              hipStream_t stream) {
    const float* x    = (const float*)d_in[0];
    const float* keep = (const float*)d_in[2];
    float* out = (float*)d_out;

    // ws: (reserved 128KB) | S 128KB | cnts 128B | listP 128KB | listK 128KB | colM 8MB
    char* ws = (char*)d_ws;
    float* S    = (float*)(ws + (128 << 10));
    int*   cntP = (int*)(ws + (256 << 10));
    int*   cntK = cntP + 16;
    int*   listP = (int*)(ws + (256 << 10) + 128);
    int*   listK = listP + BB * NN;
    float4* colM = (float4*)(ws + (1 << 20));

    k_pre<<<512, TPB, 0, stream>>>(keep, out, S, cntP, cntK, listP, listK);

    dim3 gp2(NN / TPB, BB);
    k_pre2<<<gp2, TPB, 0, stream>>>(x, cntK, listK, colM);

    // 1-D grid: b = id & 15 (XCD pinning), tile = id >> 4.
    k_argmax<<<(NN / MROWS) * BB, 512, 0, stream>>>(x, colM, cntP, cntK,
                                                    listP, listK, S, out);

    k_finalize<<<(BB * NN * CC / 4) / TPB, TPB, 0, stream>>>(x, S, out);
}